// Round 5
// baseline (677.269 us; speedup 1.0000x reference)
//
#include <hip/hip_runtime.h>
#include <hip/hip_bf16.h>

// RGAT encoder, round 5:
//  - bf16 MFMA GEMM with fused attention-logit epilogue (unchanged)
//  - CSR keyed by (node, relation): 3 contiguous sub-segments per node ->
//    relation is a compile-time constant of an unrolled loop (branch-free)
//  - aggregate: block per node, HALF-WAVE per edge (ushort8 = 16B/lane),
//    per-relation register accumulators, shfl_xor(32) fold + LDS combine.

#define RN 100000
#define RE 500000
#define RH 4
#define RIN 256
#define RR 3
#define RHF 256
#define NE3 (RR * RE)
#define N3  (RR * RN)

typedef __attribute__((ext_vector_type(8))) short short8;
typedef __attribute__((ext_vector_type(4))) float f32x4;

static __device__ __forceinline__ float b2f(unsigned short u) {
  return __uint_as_float(((unsigned int)u) << 16);
}
static __device__ __forceinline__ unsigned short f2b(float f) {
  unsigned int u = __float_as_uint(f);
  u += 0x7FFF + ((u >> 16) & 1);   // RNE
  return (unsigned short)(u >> 16);
}

// ---------------- conversions ----------------
__global__ __launch_bounds__(256) void rgat_convx(
    const float* __restrict__ x, unsigned short* __restrict__ xb) {
  const size_t i = ((size_t)blockIdx.x * 256 + threadIdx.x) * 4;
  if (i >= (size_t)RN * RIN) return;
  const float4 v = *(const float4*)(x + i);
  ushort4 o;
  o.x = f2b(v.x); o.y = f2b(v.y); o.z = f2b(v.z); o.w = f2b(v.w);
  *(ushort4*)(xb + i) = o;
}

// W[r][k][n] f32 -> Wbt[r][n][k] bf16
__global__ __launch_bounds__(256) void rgat_convw(
    const float* __restrict__ W, unsigned short* __restrict__ wbt) {
  const int o = blockIdx.x * 256 + threadIdx.x;
  if (o >= RR * RIN * RHF) return;
  const int r = o / (RIN * RHF);
  const int rem = o - r * (RIN * RHF);
  const int n = rem >> 8;
  const int k = rem & 255;
  wbt[o] = f2b(W[r * (RIN * RHF) + k * RHF + n]);
}

// ------- GEMM: zb[r] = xb @ Wbt[r]^T (bf16, f32 acc) + fused el/er ----------
__global__ __launch_bounds__(256) void rgat_gemm_bf16(
    const unsigned short* __restrict__ xb, const unsigned short* __restrict__ wbt,
    unsigned short* __restrict__ zb, const float* __restrict__ al,
    const float* __restrict__ ar, float* __restrict__ el,
    float* __restrict__ er) {
  __shared__ unsigned short As[128 * 32];
  __shared__ unsigned short Bs[128 * 32];
  const int tid = threadIdx.x;
  const int lane = tid & 63, wid = tid >> 6;
  const int wr = wid >> 1, wc = wid & 1;
  const int m0 = blockIdx.x * 128;
  const int n0 = blockIdx.y * 128;
  const int r  = blockIdx.z;

  f32x4 acc[4][4] = {};
  const unsigned short* Bbase = wbt + (size_t)r * (RIN * RHF);

  for (int k0 = 0; k0 < RIN; k0 += 32) {
#pragma unroll
    for (int i = 0; i < 2; ++i) {
      const int c = wid * 128 + i * 64 + lane;
      const int row = c >> 2, c4 = c & 3;
      const unsigned short* ga = xb + (size_t)(m0 + row) * RIN + k0 + c4 * 8;
      __builtin_amdgcn_global_load_lds(
          (const __attribute__((address_space(1))) void*)ga,
          (__attribute__((address_space(3))) void*)(As + (wid * 128 + i * 64) * 8),
          16, 0, 0);
      const unsigned short* gb = Bbase + (size_t)(n0 + row) * RIN + k0 + c4 * 8;
      __builtin_amdgcn_global_load_lds(
          (const __attribute__((address_space(1))) void*)gb,
          (__attribute__((address_space(3))) void*)(Bs + (wid * 128 + i * 64) * 8),
          16, 0, 0);
    }
    asm volatile("s_waitcnt vmcnt(0)" ::: "memory");
    __syncthreads();

    short8 af[4], bfr[4];
#pragma unroll
    for (int mi = 0; mi < 4; ++mi)
      af[mi] = *(const short8*)(As + ((wr * 64 + mi * 16 + (lane & 15)) * 32 + (lane >> 4) * 8));
#pragma unroll
    for (int ni = 0; ni < 4; ++ni)
      bfr[ni] = *(const short8*)(Bs + ((wc * 64 + ni * 16 + (lane & 15)) * 32 + (lane >> 4) * 8));
#pragma unroll
    for (int mi = 0; mi < 4; ++mi)
#pragma unroll
      for (int ni = 0; ni < 4; ++ni)
        acc[mi][ni] = __builtin_amdgcn_mfma_f32_16x16x32_bf16(af[mi], bfr[ni], acc[mi][ni], 0, 0, 0);
    __syncthreads();
  }

  const int head = blockIdx.y * 2 + wc;
  float alv[4], arv[4];
#pragma unroll
  for (int ni = 0; ni < 4; ++ni) {
    alv[ni] = al[r * RHF + head * 64 + ni * 16 + (lane & 15)];
    arv[ni] = ar[r * RHF + head * 64 + ni * 16 + (lane & 15)];
  }

  const int mbase = m0 + wr * 64;
#pragma unroll
  for (int mi = 0; mi < 4; ++mi) {
#pragma unroll
    for (int q = 0; q < 4; ++q) {
      const int m = mbase + mi * 16 + (lane >> 4) * 4 + q;
      float pl = 0.f, pr = 0.f;
#pragma unroll
      for (int ni = 0; ni < 4; ++ni) {
        pl += acc[mi][ni][q] * alv[ni];
        pr += acc[mi][ni][q] * arv[ni];
      }
#pragma unroll
      for (int off = 1; off < 16; off <<= 1) {
        pl += __shfl_xor(pl, off);
        pr += __shfl_xor(pr, off);
      }
      if (m < RN) {
        if ((lane & 15) == 0) {
          el[(size_t)(r * (size_t)RN + m) * RH + head] = pl;
          er[(size_t)(r * (size_t)RN + m) * RH + head] = pr;
        }
        unsigned short* zrow = zb + (size_t)r * ((size_t)RN * RHF) + (size_t)m * RHF
                               + n0 + wc * 64 + (lane & 15);
#pragma unroll
        for (int ni = 0; ni < 4; ++ni) zrow[ni * 16] = f2b(acc[mi][ni][q]);
      }
    }
  }
}

// ---------------- CSR build keyed by (node, relation) ----------------
__global__ __launch_bounds__(256) void rgat_hist(
    const int* __restrict__ dst, int* __restrict__ deg2) {
  const int i = blockIdx.x * 256 + threadIdx.x;
  if (i >= NE3) return;
  const int r = i / RE;
  atomicAdd(&deg2[dst[i] * RR + r], 1);
}

__global__ __launch_bounds__(256) void rgat_scan1(
    const int* __restrict__ deg, int* __restrict__ offs, int* __restrict__ bsum) {
  __shared__ int sh[256];
  const int tid = threadIdx.x;
  const int base = blockIdx.x * 1024 + tid * 4;
  int v[4]; int s = 0;
#pragma unroll
  for (int j = 0; j < 4; ++j) {
    v[j] = (base + j < N3) ? deg[base + j] : 0;
    s += v[j];
  }
  sh[tid] = s;
  __syncthreads();
  for (int off = 1; off < 256; off <<= 1) {
    int t = (tid >= off) ? sh[tid - off] : 0;
    __syncthreads();
    sh[tid] += t;
    __syncthreads();
  }
  int run = sh[tid] - s;
  if (tid == 255) bsum[blockIdx.x] = sh[255];
#pragma unroll
  for (int j = 0; j < 4; ++j) {
    if (base + j < N3) offs[base + j] = run;
    run += v[j];
  }
}

__global__ __launch_bounds__(512) void rgat_scan2(int* __restrict__ bsum, int nb) {
  __shared__ int sh[512];
  const int tid = threadIdx.x;
  const int v = (tid < nb) ? bsum[tid] : 0;
  sh[tid] = v;
  __syncthreads();
  for (int off = 1; off < 512; off <<= 1) {
    int t = (tid >= off) ? sh[tid - off] : 0;
    __syncthreads();
    sh[tid] += t;
    __syncthreads();
  }
  if (tid < nb) bsum[tid] = sh[tid] - v;
}

__global__ __launch_bounds__(256) void rgat_scan3(
    int* __restrict__ offs, const int* __restrict__ bsum) {
  const int base = blockIdx.x * 1024 + threadIdx.x * 4;
  const int b = bsum[blockIdx.x];
#pragma unroll
  for (int j = 0; j < 4; ++j)
    if (base + j < N3) offs[base + j] += b;
}

// scatter: csrc[pos]=src, cee[pos]=exp numerators; offs2 keyed (node,relation)
__global__ __launch_bounds__(256) void rgat_scatter(
    const int* __restrict__ src, const int* __restrict__ dst,
    const float* __restrict__ el, const float* __restrict__ er,
    int* __restrict__ offs2, int* __restrict__ csrc,
    float4* __restrict__ cee) {
  const int i = blockIdx.x * 256 + threadIdx.x;
  if (i >= NE3) return;
  const int r = i / RE;
  const int s = src[i];
  const int d = dst[i];
  const int pos = atomicAdd(&offs2[d * RR + r], 1);
  const float4 elv = *(const float4*)(el + (size_t)(r * (size_t)RN + s) * RH);
  const float4 erv = *(const float4*)(er + (size_t)(r * (size_t)RN + d) * RH);
  float e0 = elv.x + erv.x, e1 = elv.y + erv.y, e2 = elv.z + erv.z, e3 = elv.w + erv.w;
  e0 = e0 > 0.f ? e0 : 0.2f * e0;
  e1 = e1 > 0.f ? e1 : 0.2f * e1;
  e2 = e2 > 0.f ? e2 : 0.2f * e2;
  e3 = e3 > 0.f ? e3 : 0.2f * e3;
  csrc[pos] = s;
  cee[pos] = make_float4(__expf(e0), __expf(e1), __expf(e2), __expf(e3));
}

// -------- aggregate: block per node; half-wave (32 lanes) per edge -----------
__global__ __launch_bounds__(256) void rgat_aggregate(
    const unsigned short* __restrict__ zb, const int* __restrict__ csrc,
    const float* __restrict__ ceef, const int* __restrict__ deg2,
    const int* __restrict__ offs2, const float* __restrict__ bias,
    float* __restrict__ out) {
  __shared__ float shn[4][RR][RHF];   // 12 KB
  __shared__ float shd[4][RR][RH];
  const int n = blockIdx.x;
  const int tid = threadIdx.x;
  const int wid = tid >> 6, lane = tid & 63;
  const int hw = tid >> 5;            // half-wave id 0..7
  const int sub = lane & 31;          // lane within half-wave
  const int h = sub >> 3;             // head for my 8 columns
  const int c = sub * 8;              // my 8 columns

  float accr[RR][8];
  float denr[RR];
#pragma unroll
  for (int r = 0; r < RR; ++r) {
    denr[r] = 0.f;
#pragma unroll
    for (int k = 0; k < 8; ++k) accr[r][k] = 0.f;
  }

#pragma unroll
  for (int r = 0; r < RR; ++r) {
    const int key = n * RR + r;
    const int dr = deg2[key];
    const int end = offs2[key];
    const int start = end - dr;
    const unsigned short* zB = zb + (size_t)r * ((size_t)RN * RHF) + c;
    for (int t = hw; t < dr; t += 8) {
      const int p = start + t;
      const int s = csrc[p];
      const float a = ceef[p * 4 + h];
      const short8 zv = *(const short8*)(zB + (size_t)s * RHF);
      denr[r] += a;
#pragma unroll
      for (int k = 0; k < 8; ++k)
        accr[r][k] += a * b2f((unsigned short)zv[k]);
    }
  }

  // fold half-waves (lane L gets L^32 partner's partials)
#pragma unroll
  for (int r = 0; r < RR; ++r) {
    denr[r] += __shfl_xor(denr[r], 32);
#pragma unroll
    for (int k = 0; k < 8; ++k) accr[r][k] += __shfl_xor(accr[r][k], 32);
  }

  if (lane < 32) {
#pragma unroll
    for (int r = 0; r < RR; ++r) {
      *(float4*)&shn[wid][r][c] = make_float4(accr[r][0], accr[r][1], accr[r][2], accr[r][3]);
      *(float4*)&shn[wid][r][c + 4] = make_float4(accr[r][4], accr[r][5], accr[r][6], accr[r][7]);
      if ((sub & 7) == 0) shd[wid][r][h] = denr[r];
    }
  }
  __syncthreads();

  const int col = tid;
  const int hh = col >> 6;
  float v = bias[col] + bias[RHF + col] + bias[2 * RHF + col];
#pragma unroll
  for (int r = 0; r < RR; ++r) {
    const float dn = shd[0][r][hh] + shd[1][r][hh] + shd[2][r][hh] + shd[3][r][hh];
    const float nm = shn[0][r][col] + shn[1][r][col] + shn[2][r][col] + shn[3][r][col];
    v += (dn > 0.f) ? nm / dn : 0.f;
  }
  v = v > 0.f ? v : (__expf(v) - 1.f);
  out[(size_t)n * RHF + col] = v;
}

extern "C" void kernel_launch(void* const* d_in, const int* in_sizes, int n_in,
                              void* d_out, int out_size, void* d_ws, size_t ws_size,
                              hipStream_t stream) {
  const float* x    = (const float*)d_in[0];
  const float* W    = (const float*)d_in[1];
  const float* al   = (const float*)d_in[2];
  const float* ar   = (const float*)d_in[3];
  const float* bias = (const float*)d_in[4];
  const int*   src  = (const int*)d_in[5];
  const int*   dst  = (const int*)d_in[6];
  float* out = (float*)d_out;

  // workspace layout (bytes), total ~248 MB
  char* p = (char*)d_ws;
  unsigned short* xb  = (unsigned short*)p; p += (size_t)RN * RIN * 2;        // 51.2 MB
  unsigned short* wbt = (unsigned short*)p; p += (size_t)RR * RIN * RHF * 2;  // 0.39 MB
  unsigned short* zb  = (unsigned short*)p; p += (size_t)RR * RN * RHF * 2;   // 153.6 MB
  float* el    = (float*)p;  p += (size_t)RR * RN * RH * 4;                   // 4.8 MB
  float* er    = (float*)p;  p += (size_t)RR * RN * RH * 4;                   // 4.8 MB
  int* deg2    = (int*)p;    p += (size_t)N3 * 4;                             // 1.2 MB
  int* offs2   = (int*)p;    p += (size_t)N3 * 4;                             // 1.2 MB
  int* csrc    = (int*)p;    p += (size_t)NE3 * 4;                            // 6.0 MB
  float4* cee  = (float4*)p; p += (size_t)NE3 * 16;                           // 24.0 MB
  int* bsum    = (int*)p;    p += 2048;

  const int NB1 = (N3 + 1023) / 1024;   // 293

  hipMemsetAsync(deg2, 0, (size_t)N3 * 4, stream);

  rgat_convx<<<(RN * RIN / 4 + 255) / 256, 256, 0, stream>>>(x, xb);
  rgat_convw<<<(RR * RIN * RHF + 255) / 256, 256, 0, stream>>>(W, wbt);

  rgat_hist<<<(NE3 + 255) / 256, 256, 0, stream>>>(dst, deg2);
  rgat_scan1<<<NB1, 256, 0, stream>>>(deg2, offs2, bsum);
  rgat_scan2<<<1, 512, 0, stream>>>(bsum, NB1);
  rgat_scan3<<<NB1, 256, 0, stream>>>(offs2, bsum);

  rgat_gemm_bf16<<<dim3((RN + 127) / 128, RHF / 128, RR), 256, 0, stream>>>(
      xb, wbt, zb, al, ar, el, er);

  rgat_scatter<<<(NE3 + 255) / 256, 256, 0, stream>>>(src, dst, el, er, offs2,
                                                      csrc, cee);

  rgat_aggregate<<<RN, 256, 0, stream>>>(zb, csrc, (const float*)cee, deg2,
                                         offs2, bias, out);
}